// Round 1
// baseline (122.411 us; speedup 1.0000x reference)
//
#include <hip/hip_runtime.h>
#include <hip/hip_bf16.h>

// ---------------------------------------------------------------------------
// Modnet2: out[i] = sum_j y_j * ( tanh( tanh(A_i + B_j) @ W2 + b2 ) @ W3 + b3 )
//   A[i][h] = input[i,0:2] @ W1[0:2,h]
//   B[j][h] = quad_x[j,0:2] @ W1[2:4,h] + b1[h]
//   y[j]    = prod_d sin(pi * eq * quad_x[j,d])
// Heavy part: per-pair 128x128 matvec -> batched bf16 MFMA GEMM.
// ---------------------------------------------------------------------------

using short8 = __attribute__((ext_vector_type(8))) short;   // 8 bf16 = 4 VGPR
using f32x4  = __attribute__((ext_vector_type(4))) float;   // MFMA C/D frag

#define N_IN   2048
#define M_Q    512
#define H_DIM  128

// ws byte offsets (16B aligned)
#define WS_A_OFF     0x000000u   // 2048*128 f32  = 1 MiB
#define WS_B_OFF     0x100000u   //  512*128 f32  = 256 KiB
#define WS_Y_OFF     0x140000u   //  512 f32
#define WS_SUMY_OFF  0x140800u   //  1 f32
#define WS_W2T_OFF   0x141000u   //  128*128 bf16 = 32 KiB
#define WS_SPART_OFF 0x150000u   //  JC * 2048*128 f32

#define PI_F 3.14159265358979323846f

// tanh(x) = 1 - 2/(1 + e^{2x}) ; e^{2x} = exp2(x * 2*log2(e)).
// Saturates correctly at +-inf; 2 transcendental ops, ~4 VALU.
__device__ __forceinline__ float tanh_fast(float x) {
    float t = __builtin_amdgcn_exp2f(x * 2.885390081777927f);
    return 1.0f - 2.0f * __builtin_amdgcn_rcpf(1.0f + t);
}

__device__ __forceinline__ unsigned short bf16b(float f) {
    __hip_bfloat16 h = __float2bfloat16(f);   // round-to-nearest-even
    unsigned short u;
    __builtin_memcpy(&u, &h, 2);
    return u;
}

// build one MFMA A-fragment: 8 bf16 = tanh(a + b) for 8 consecutive k
__device__ __forceinline__ void conv8(const float4& a0, const float4& a1,
                                      const float4& b0, const float4& b1,
                                      short8& dst) {
    dst[0] = (short)bf16b(tanh_fast(a0.x + b0.x));
    dst[1] = (short)bf16b(tanh_fast(a0.y + b0.y));
    dst[2] = (short)bf16b(tanh_fast(a0.z + b0.z));
    dst[3] = (short)bf16b(tanh_fast(a0.w + b0.w));
    dst[4] = (short)bf16b(tanh_fast(a1.x + b1.x));
    dst[5] = (short)bf16b(tanh_fast(a1.y + b1.y));
    dst[6] = (short)bf16b(tanh_fast(a1.z + b1.z));
    dst[7] = (short)bf16b(tanh_fast(a1.w + b1.w));
}

// ---------------------------------------------------------------------------
// k_pre: A, B, y, sumy, W2^T(bf16)
// grid: 1345 x 256
// ---------------------------------------------------------------------------
__global__ void k_pre(const float* __restrict__ input, const float* __restrict__ qx,
                      const float* __restrict__ eq, const float* __restrict__ W1,
                      const float* __restrict__ b1, const float* __restrict__ W2,
                      float* __restrict__ ws) {
    int b = blockIdx.x, t = threadIdx.x;
    float* A = ws + (WS_A_OFF >> 2);
    float* B = ws + (WS_B_OFF >> 2);
    float* Y = ws + (WS_Y_OFF >> 2);
    unsigned short* W2T = (unsigned short*)((char*)ws + WS_W2T_OFF);

    if (b < 1024) {                       // A[i][h]
        int idx = b * 256 + t;
        int i = idx >> 7, h = idx & 127;
        A[idx] = input[2 * i] * W1[h] + input[2 * i + 1] * W1[128 + h];
    } else if (b < 1280) {                // B[j][h] (+ b1)
        int idx = (b - 1024) * 256 + t;
        int j = idx >> 7, h = idx & 127;
        B[idx] = qx[2 * j] * W1[256 + h] + qx[2 * j + 1] * W1[384 + h] + b1[h];
    } else if (b < 1344) {                // W2T[n][k] = bf16(W2[k][n])
        int idx = (b - 1280) * 256 + t;
        int n = idx >> 7, k = idx & 127;
        W2T[idx] = bf16b(W2[k * 128 + n]);
    } else {                              // y[j], sumy
        float e = eq[0];
        float s = 0.f;
        for (int rep = 0; rep < 2; ++rep) {
            int j = t + rep * 256;
            float yv = sinf(PI_F * e * qx[2 * j]) * sinf(PI_F * e * qx[2 * j + 1]);
            Y[j] = yv;
            s += yv;
        }
        __shared__ float red[4];
        for (int off = 32; off; off >>= 1) s += __shfl_down(s, off);
        if ((t & 63) == 0) red[t >> 6] = s;
        __syncthreads();
        if (t == 0) ws[WS_SUMY_OFF >> 2] = red[0] + red[1] + red[2] + red[3];
    }
}

// ---------------------------------------------------------------------------
// k_main: Spart[jc][i][n] = sum_{j in chunk} y_j * tanh( tanh(A_i+B_j)@W2 + b2 )
// grid: (32 i-blocks, JC j-chunks) x 256 threads (4 waves).
// wave = 32 i x 64 n tile; A-addends + W2 frags register-resident.
// mfma_f32_16x16x32_bf16 layout:
//   A: lane l -> row l&15, k = (l>>4)*8 + e      (8 bf16 / lane)
//   B: lane l -> k = (l>>4)*8 + e, col l&15
//   D: lane l reg r -> row (l>>4)*4 + r, col l&15
// ---------------------------------------------------------------------------
__global__ __launch_bounds__(256, 2)
void k_main(const float* __restrict__ A, const float* __restrict__ B,
            const float* __restrict__ Y, const unsigned short* __restrict__ W2T,
            const float* __restrict__ b2, float* __restrict__ Spart, int jchunk) {
    __shared__ float Bs[64 * 128];
    __shared__ float ys[64];

    int t = threadIdx.x;
    int wave = t >> 6, lane = t & 63;
    int l16 = lane & 15, lg = lane >> 4;
    int ibW = blockIdx.x * 64 + (wave >> 1) * 32;   // wave's first i
    int nbW = (wave & 1) * 64;                      // wave's first n
    int jbase = blockIdx.y * jchunk;

    // stage B chunk rows + y chunk into LDS (coalesced)
    int nf4 = (jchunk * 128) >> 2;                  // float4 count
    for (int off4 = t; off4 < nf4; off4 += 256) {
        *(float4*)&Bs[off4 * 4] = *(const float4*)&B[jbase * 128 + off4 * 4];
    }
    if (t < jchunk) ys[t] = Y[jbase + t];
    __syncthreads();

    // A-addends: aa[rb][kc][2] (8 f32 each) -- j-independent, keep in VGPRs
    float4 aa[2][4][2];
#pragma unroll
    for (int rb = 0; rb < 2; ++rb)
#pragma unroll
        for (int kc = 0; kc < 4; ++kc) {
            const float* p = &A[(ibW + rb * 16 + l16) * 128 + kc * 32 + lg * 8];
            aa[rb][kc][0] = *(const float4*)p;
            aa[rb][kc][1] = *(const float4*)(p + 4);
        }

    // W2 B-fragments: wf[nb][kc], from W2T[n][k] (8 consecutive k = 16B load)
    short8 wf[4][4];
#pragma unroll
    for (int nb = 0; nb < 4; ++nb)
#pragma unroll
        for (int kc = 0; kc < 4; ++kc)
            wf[nb][kc] = *(const short8*)&W2T[(nbW + nb * 16 + l16) * 128 + kc * 32 + lg * 8];

    float b2v[4];
#pragma unroll
    for (int nb = 0; nb < 4; ++nb) b2v[nb] = b2[nbW + nb * 16 + l16];

    f32x4 acc[2][4] = {};   // y-weighted running sum (fp32)

#pragma unroll 1
    for (int jj = 0; jj < jchunk; ++jj) {
        // C initialized with b2 (col = n for every reg)
        f32x4 o[2][4];
#pragma unroll
        for (int rb = 0; rb < 2; ++rb)
#pragma unroll
            for (int nb = 0; nb < 4; ++nb) {
                o[rb][nb][0] = b2v[nb]; o[rb][nb][1] = b2v[nb];
                o[rb][nb][2] = b2v[nb]; o[rb][nb][3] = b2v[nb];
            }

#pragma unroll
        for (int kc = 0; kc < 4; ++kc) {
            const float* bp = &Bs[jj * 128 + kc * 32 + lg * 8];
            float4 bj0 = *(const float4*)bp;
            float4 bj1 = *(const float4*)(bp + 4);
            short8 av[2];
#pragma unroll
            for (int rb = 0; rb < 2; ++rb)
                conv8(aa[rb][kc][0], aa[rb][kc][1], bj0, bj1, av[rb]);
#pragma unroll
            for (int nb = 0; nb < 4; ++nb)
#pragma unroll
                for (int rb = 0; rb < 2; ++rb)
                    o[rb][nb] = __builtin_amdgcn_mfma_f32_16x16x32_bf16(
                        av[rb], wf[nb][kc], o[rb][nb], 0, 0, 0);
        }

        float yj = ys[jj];
#pragma unroll
        for (int rb = 0; rb < 2; ++rb)
#pragma unroll
            for (int nb = 0; nb < 4; ++nb)
#pragma unroll
                for (int r = 0; r < 4; ++r)
                    acc[rb][nb][r] += yj * tanh_fast(o[rb][nb][r]);
    }

    // write partial S for this j-chunk (deterministic, no atomics)
    float* Sp = Spart + (size_t)blockIdx.y * (N_IN * H_DIM);
#pragma unroll
    for (int rb = 0; rb < 2; ++rb)
#pragma unroll
        for (int nb = 0; nb < 4; ++nb)
#pragma unroll
            for (int r = 0; r < 4; ++r) {
                int i = ibW + rb * 16 + lg * 4 + r;
                int n = nbW + nb * 16 + l16;
                Sp[i * H_DIM + n] = acc[rb][nb][r];
            }
}

// ---------------------------------------------------------------------------
// k_fin: out[i] = (sum_jc Spart[jc][i][:]) @ W3 + b3 * sumy
// grid: 512 x 256 (one wave per i)
// ---------------------------------------------------------------------------
__global__ void k_fin(const float* __restrict__ Spart, const float* __restrict__ W3,
                      const float* __restrict__ b3, const float* __restrict__ ws,
                      float* __restrict__ out, int JC) {
    int wave = threadIdx.x >> 6, lane = threadIdx.x & 63;
    int i = blockIdx.x * 4 + wave;
    float w3a = W3[lane], w3b = W3[lane + 64];
    float acc = 0.f;
    for (int jc = 0; jc < JC; ++jc) {
        const float* p = &Spart[((size_t)jc * N_IN + i) * H_DIM];
        acc += p[lane] * w3a + p[lane + 64] * w3b;
    }
    for (int off = 32; off; off >>= 1) acc += __shfl_down(acc, off);
    if (lane == 0) out[i] = acc + b3[0] * ws[WS_SUMY_OFF >> 2];
}

// ---------------------------------------------------------------------------
extern "C" void kernel_launch(void* const* d_in, const int* in_sizes, int n_in,
                              void* d_out, int out_size, void* d_ws, size_t ws_size,
                              hipStream_t stream) {
    const float* input = (const float*)d_in[0];
    const float* qx    = (const float*)d_in[1];
    const float* eq    = (const float*)d_in[2];
    const float* W1    = (const float*)d_in[3];
    const float* b1    = (const float*)d_in[4];
    const float* W2    = (const float*)d_in[5];
    const float* b2    = (const float*)d_in[6];
    const float* W3    = (const float*)d_in[7];
    const float* b3    = (const float*)d_in[8];
    float* out = (float*)d_out;
    float* ws  = (float*)d_ws;

    // JC j-chunks of 512/JC quad points each; Spart = JC MiB.
    size_t need16 = (size_t)WS_SPART_OFF + 16ull * N_IN * H_DIM * 4;
    int JC = (ws_size >= need16) ? 16 : 8;
    int jchunk = M_Q / JC;

    const float* A   = ws + (WS_A_OFF >> 2);
    const float* B   = ws + (WS_B_OFF >> 2);
    const float* Y   = ws + (WS_Y_OFF >> 2);
    const unsigned short* W2T = (const unsigned short*)((char*)d_ws + WS_W2T_OFF);
    float* Spart = (float*)((char*)d_ws + WS_SPART_OFF);

    k_pre<<<1345, 256, 0, stream>>>(input, qx, eq, W1, b1, W2, ws);
    k_main<<<dim3(32, JC), 256, 0, stream>>>(A, B, Y, W2T, b2, Spart, jchunk);
    k_fin<<<512, 256, 0, stream>>>(Spart, W3, b3, ws, out, JC);
}

// Round 2
// 83.058 us; speedup vs baseline: 1.4738x; 1.4738x over previous
//
#include <hip/hip_runtime.h>
#include <hip/hip_bf16.h>

// ---------------------------------------------------------------------------
// Modnet2: out[i] = sum_j y_j * ( tanh( tanh(A_i + B_j) @ W2 + b2 ) @ W3 + b3 )
//   A[i][h] = s*(input[i,0:2] @ W1[0:2,h])          (s = 2*log2(e) folded in)
//   B[j][h] = s*(quad_x[j,0:2] @ W1[2:4,h] + b1[h])
//   W2T/b2 also pre-scaled by s, so tanh(x) = 1 - 2*rcp(1 + exp2(x_scaled)).
// k_main: block = 64 i x 128 n x 32 j. 4 waves, each 32i x 64n.
// Layer-1 bf16 fragments are computed ONCE: wave (ih,p) converts k-chunks
// {2p,2p+1} for its i-half, exchanges with partner wave via LDS (dbuf,
// 1 barrier/j). W3 dot fused into epilogue -> tiny partial buffer.
// ---------------------------------------------------------------------------

using short8 = __attribute__((ext_vector_type(8))) short;   // 8 bf16 = 4 VGPR
using f32x4  = __attribute__((ext_vector_type(4))) float;   // MFMA C/D frag

#define N_IN   2048
#define M_Q    512
#define H_DIM  128
#define JC     16
#define JCHUNK 32      // M_Q / JC

// ws byte offsets
#define WS_A_OFF     0x000000u   // 2048*128 f32 = 1 MiB   (pre-scaled)
#define WS_B_OFF     0x100000u   //  512*128 f32 = 256 KiB (pre-scaled)
#define WS_Y_OFF     0x140000u   //  512 f32
#define WS_SUMY_OFF  0x140800u   //  1 f32
#define WS_W2T_OFF   0x141000u   //  128*128 bf16 = 32 KiB (pre-scaled)
#define WS_SP_OFF    0x150000u   //  32 * 2048 f32 = 256 KiB (n-reduced partials)

#define PI_F   3.14159265358979323846f
#define TSCALE 2.885390081777927f   // 2*log2(e)

// x pre-scaled by TSCALE: tanh = 1 - 2/(1+e^{2x}) = 1 - 2*rcp(1+exp2(xs))
__device__ __forceinline__ float tanh_pre(float xs) {
    float t = __builtin_amdgcn_exp2f(xs);
    float r = __builtin_amdgcn_rcpf(1.0f + t);
    return __builtin_fmaf(-2.0f, r, 1.0f);
}

__device__ __forceinline__ unsigned short bf16b(float f) {
    __hip_bfloat16 h = __float2bfloat16(f);   // RNE
    unsigned short u;
    __builtin_memcpy(&u, &h, 2);
    return u;
}

// one MFMA A-fragment: 8 bf16 = tanh(a + b), inputs pre-scaled
__device__ __forceinline__ void conv8(const float4& a0, const float4& a1,
                                      const float4& b0, const float4& b1,
                                      short8& dst) {
    dst[0] = (short)bf16b(tanh_pre(a0.x + b0.x));
    dst[1] = (short)bf16b(tanh_pre(a0.y + b0.y));
    dst[2] = (short)bf16b(tanh_pre(a0.z + b0.z));
    dst[3] = (short)bf16b(tanh_pre(a0.w + b0.w));
    dst[4] = (short)bf16b(tanh_pre(a1.x + b1.x));
    dst[5] = (short)bf16b(tanh_pre(a1.y + b1.y));
    dst[6] = (short)bf16b(tanh_pre(a1.z + b1.z));
    dst[7] = (short)bf16b(tanh_pre(a1.w + b1.w));
}

// ---------------------------------------------------------------------------
// k_pre: A, B (scaled), y, sumy, W2T (scaled bf16)
// ---------------------------------------------------------------------------
__global__ void k_pre(const float* __restrict__ input, const float* __restrict__ qx,
                      const float* __restrict__ eq, const float* __restrict__ W1,
                      const float* __restrict__ b1, const float* __restrict__ W2,
                      float* __restrict__ ws) {
    int b = blockIdx.x, t = threadIdx.x;
    float* A = ws + (WS_A_OFF >> 2);
    float* B = ws + (WS_B_OFF >> 2);
    float* Y = ws + (WS_Y_OFF >> 2);
    unsigned short* W2T = (unsigned short*)((char*)ws + WS_W2T_OFF);

    if (b < 1024) {                       // A[i][h] (scaled)
        int idx = b * 256 + t;
        int i = idx >> 7, h = idx & 127;
        A[idx] = TSCALE * (input[2 * i] * W1[h] + input[2 * i + 1] * W1[128 + h]);
    } else if (b < 1280) {                // B[j][h] (scaled, + b1)
        int idx = (b - 1024) * 256 + t;
        int j = idx >> 7, h = idx & 127;
        B[idx] = TSCALE * (qx[2 * j] * W1[256 + h] + qx[2 * j + 1] * W1[384 + h] + b1[h]);
    } else if (b < 1344) {                // W2T[n][k] = bf16(s*W2[k][n])
        int idx = (b - 1280) * 256 + t;
        int n = idx >> 7, k = idx & 127;
        W2T[idx] = bf16b(TSCALE * W2[k * 128 + n]);
    } else {                              // y[j], sumy
        float e = eq[0];
        float s = 0.f;
        for (int rep = 0; rep < 2; ++rep) {
            int j = t + rep * 256;
            float yv = sinf(PI_F * e * qx[2 * j]) * sinf(PI_F * e * qx[2 * j + 1]);
            Y[j] = yv;
            s += yv;
        }
        __shared__ float red[4];
        for (int off = 32; off; off >>= 1) s += __shfl_down(s, off);
        if ((t & 63) == 0) red[t >> 6] = s;
        __syncthreads();
        if (t == 0) ws[WS_SUMY_OFF >> 2] = red[0] + red[1] + red[2] + red[3];
    }
}

// ---------------------------------------------------------------------------
// k_main. grid (32 i-blocks, 16 j-chunks) x 256.
// wave w: ih=w>>1 (i-half, 32 rows), p=w&1 (n-half, 64 cols; own k-chunks 2p,2p+1)
// mfma_f32_16x16x32_bf16 layout (verified in R1):
//   A: lane l -> row l&15, k=(l>>4)*8+e ; B: lane l -> col l&15, k=(l>>4)*8+e
//   D: lane l reg r -> row (l>>4)*4+r, col l&15
// ---------------------------------------------------------------------------
__global__ __launch_bounds__(256, 2)
void k_main(const float* __restrict__ A, const float* __restrict__ B,
            const float* __restrict__ Y, const unsigned short* __restrict__ W2T,
            const float* __restrict__ b2, const float* __restrict__ W3,
            float* __restrict__ Sp) {
    __shared__ float Bs[JCHUNK * 128];                  // 16 KB
    __shared__ float ys[JCHUNK];
    __shared__ unsigned short xbuf[2 * 2 * 4 * 2 * 512]; // dbuf x ih x kc x rb x 1KB = 32 KB

    int t = threadIdx.x;
    int wave = t >> 6, lane = t & 63;
    int l16 = lane & 15, lg = lane >> 4;
    int ih = wave >> 1, p = wave & 1;
    int ibW = blockIdx.x * 64 + ih * 32;
    int jbase = blockIdx.y * JCHUNK;
    int myk0 = 2 * p;                 // own k-chunk base
    int otk0 = 2 * (1 - p);           // partner's k-chunk base

    // stage B chunk + y into LDS (coalesced)
    for (int off4 = t; off4 < (JCHUNK * 128) >> 2; off4 += 256)
        *(float4*)&Bs[off4 * 4] = *(const float4*)&B[jbase * 128 + off4 * 4];
    if (t < JCHUNK) ys[t] = Y[jbase + t];

    // A-addends for OWN k-chunks only: aa[rb][kco][2]
    float4 aa[2][2][2];
#pragma unroll
    for (int rb = 0; rb < 2; ++rb)
#pragma unroll
        for (int kco = 0; kco < 2; ++kco) {
            const float* pa = &A[(ibW + rb * 16 + l16) * 128 + (myk0 + kco) * 32 + lg * 8];
            aa[rb][kco][0] = *(const float4*)pa;
            aa[rb][kco][1] = *(const float4*)(pa + 4);
        }

    // W2 fragments: own-k and other-k sets (all 128 k for this wave's 64 n)
    short8 wfo[4][2], wfx[4][2];
#pragma unroll
    for (int nb = 0; nb < 4; ++nb)
#pragma unroll
        for (int kco = 0; kco < 2; ++kco) {
            int nrow = (p * 64 + nb * 16 + l16) * 128 + lg * 8;
            wfo[nb][kco] = *(const short8*)&W2T[nrow + (myk0 + kco) * 32];
            wfx[nb][kco] = *(const short8*)&W2T[nrow + (otk0 + kco) * 32];
        }

    float b2v[4], w3v[4];
#pragma unroll
    for (int nb = 0; nb < 4; ++nb) {
        b2v[nb] = TSCALE * b2[p * 64 + nb * 16 + l16];
        w3v[nb] = W3[p * 64 + nb * 16 + l16];
    }

    unsigned short* xw = xbuf + (ih * 4 + myk0) * 2 * 512 + lane * 8;
    unsigned short* xr = xbuf + (ih * 4 + otk0) * 2 * 512 + lane * 8;

    __syncthreads();

    f32x4 acc[2][4] = {};

#pragma unroll 1
    for (int jj = 0; jj < JCHUNK; ++jj) {
        int bsel = (jj & 1) * 8192;

        // convert own k-chunks: av[kco][rb]
        short8 av[2][2];
#pragma unroll
        for (int kco = 0; kco < 2; ++kco) {
            const float* bp = &Bs[jj * 128 + (myk0 + kco) * 32 + lg * 8];
            float4 bj0 = *(const float4*)bp;
            float4 bj1 = *(const float4*)(bp + 4);
#pragma unroll
            for (int rb = 0; rb < 2; ++rb)
                conv8(aa[rb][kco][0], aa[rb][kco][1], bj0, bj1, av[kco][rb]);
        }

        // exchange: write own frags, barrier, read partner frags
#pragma unroll
        for (int kco = 0; kco < 2; ++kco)
#pragma unroll
            for (int rb = 0; rb < 2; ++rb)
                *(short8*)(xw + bsel + (kco * 2 + rb) * 512) = av[kco][rb];

        __syncthreads();

        short8 avx[2][2];
#pragma unroll
        for (int kco = 0; kco < 2; ++kco)
#pragma unroll
            for (int rb = 0; rb < 2; ++rb)
                avx[kco][rb] = *(const short8*)(xr + bsel + (kco * 2 + rb) * 512);

        // MFMA: o = b2 + H1 @ W2  (own k first, then partner k)
        f32x4 o[2][4];
#pragma unroll
        for (int rb = 0; rb < 2; ++rb)
#pragma unroll
            for (int nb = 0; nb < 4; ++nb) {
                o[rb][nb][0] = b2v[nb]; o[rb][nb][1] = b2v[nb];
                o[rb][nb][2] = b2v[nb]; o[rb][nb][3] = b2v[nb];
            }
#pragma unroll
        for (int kco = 0; kco < 2; ++kco)
#pragma unroll
            for (int rb = 0; rb < 2; ++rb)
#pragma unroll
                for (int nb = 0; nb < 4; ++nb)
                    o[rb][nb] = __builtin_amdgcn_mfma_f32_16x16x32_bf16(
                        av[kco][rb], wfo[nb][kco], o[rb][nb], 0, 0, 0);
#pragma unroll
        for (int kco = 0; kco < 2; ++kco)
#pragma unroll
            for (int rb = 0; rb < 2; ++rb)
#pragma unroll
                for (int nb = 0; nb < 4; ++nb)
                    o[rb][nb] = __builtin_amdgcn_mfma_f32_16x16x32_bf16(
                        avx[kco][rb], wfx[nb][kco], o[rb][nb], 0, 0, 0);

        // layer-2 tanh (o pre-scaled) + y-weighted accumulate
        float yj = ys[jj];
#pragma unroll
        for (int rb = 0; rb < 2; ++rb)
#pragma unroll
            for (int nb = 0; nb < 4; ++nb)
#pragma unroll
                for (int r = 0; r < 4; ++r)
                    acc[rb][nb][r] = __builtin_fmaf(yj, tanh_pre(o[rb][nb][r]),
                                                    acc[rb][nb][r]);
    }

    // epilogue: fold W3 over this wave's 64 n, reduce across l16, write partial
    float s[2][4];
#pragma unroll
    for (int rb = 0; rb < 2; ++rb)
#pragma unroll
        for (int r = 0; r < 4; ++r) {
            float v = 0.f;
#pragma unroll
            for (int nb = 0; nb < 4; ++nb)
                v = __builtin_fmaf(acc[rb][nb][r], w3v[nb], v);
            s[rb][r] = v;
        }
#pragma unroll
    for (int m = 1; m < 16; m <<= 1)
#pragma unroll
        for (int rb = 0; rb < 2; ++rb)
#pragma unroll
            for (int r = 0; r < 4; ++r)
                s[rb][r] += __shfl_xor(s[rb][r], m);

    if (l16 == 0) {
        float* dst = Sp + (blockIdx.y * 2 + p) * N_IN;
#pragma unroll
        for (int rb = 0; rb < 2; ++rb)
#pragma unroll
            for (int r = 0; r < 4; ++r)
                dst[ibW + rb * 16 + lg * 4 + r] = s[rb][r];
    }
}

// ---------------------------------------------------------------------------
// k_fin: out[i] = sum_{s<32} Sp[s][i] + b3*sumy.  grid 8 x 256.
// ---------------------------------------------------------------------------
__global__ void k_fin(const float* __restrict__ Sp, const float* __restrict__ b3,
                      const float* __restrict__ ws, float* __restrict__ out) {
    int i = blockIdx.x * 256 + threadIdx.x;
    float acc = b3[0] * ws[WS_SUMY_OFF >> 2];
#pragma unroll
    for (int s = 0; s < 2 * JC; ++s) acc += Sp[s * N_IN + i];
    out[i] = acc;
}

// ---------------------------------------------------------------------------
extern "C" void kernel_launch(void* const* d_in, const int* in_sizes, int n_in,
                              void* d_out, int out_size, void* d_ws, size_t ws_size,
                              hipStream_t stream) {
    const float* input = (const float*)d_in[0];
    const float* qx    = (const float*)d_in[1];
    const float* eq    = (const float*)d_in[2];
    const float* W1    = (const float*)d_in[3];
    const float* b1    = (const float*)d_in[4];
    const float* W2    = (const float*)d_in[5];
    const float* b2    = (const float*)d_in[6];
    const float* W3    = (const float*)d_in[7];
    const float* b3    = (const float*)d_in[8];
    float* out = (float*)d_out;
    float* ws  = (float*)d_ws;

    const float* A = ws + (WS_A_OFF >> 2);
    const float* B = ws + (WS_B_OFF >> 2);
    const float* Y = ws + (WS_Y_OFF >> 2);
    const unsigned short* W2T = (const unsigned short*)((char*)d_ws + WS_W2T_OFF);
    float* Sp = (float*)((char*)d_ws + WS_SP_OFF);

    k_pre<<<1345, 256, 0, stream>>>(input, qx, eq, W1, b1, W2, ws);
    k_main<<<dim3(32, JC), 256, 0, stream>>>(A, B, Y, W2T, b2, W3, Sp);
    k_fin<<<8, 256, 0, stream>>>(Sp, b3, ws, out);
}